// Round 12
// baseline (21.473 us; speedup 1.0000x reference)
//
#include <hip/hip_runtime.h>
#include <math.h>

// Problem constants (match reference setup_inputs)
#define BS 32
#define NA 3
#define NC 80
#define HH 52
#define WW 52
#define TPER 50                 // targets per batch image
#define NTT (BS * TPER)         // 1600 total targets
#define HW (HH * WW)            // 2704
#define CPB (NA * HW)           // 8112 cells per batch image (divisible by 4)
#define CH (5 + NC)             // 85 channels per anchor
#define CELLS_PER_BLK 512       // 128 threads x 4 CONSECUTIVE cells each
#define CBPB 16                 // cell-blocks per batch: 16*512 = 8192 >= 8112
#define NCELLBLK (BS * CBPB)    // 512 cells-role blocks
#define NOBJBLK NTT             // 1600 obj blocks (one target each)
#define NBLK (NCELLBLK + NOBJBLK) // 2112 blocks (even)

// fast transcendentals: v_exp_f32 (2^x), v_log_f32 (log2 x), v_rcp_f32
__device__ __forceinline__ float fexp(float x) { return __builtin_amdgcn_exp2f(x * 1.4426950408889634f); }
__device__ __forceinline__ float flog(float x) { return __builtin_amdgcn_logf(x) * 0.6931471805599453f; }
__device__ __forceinline__ float sigm(float v) { return __builtin_amdgcn_rcpf(1.0f + fexp(-v)); }

__device__ __forceinline__ float wave_red(float t) {
    #pragma unroll
    for (int off = 32; off > 0; off >>= 1) t += __shfl_down(t, off);  // width 64
    return t;
}

// ws layout: float2 ws[NBLK] = {pre-weighted loss partial, n_valid contribution}

__global__ __launch_bounds__(128) void k_main(const float* __restrict__ in,
                                              const float* __restrict__ tgt,
                                              float2* __restrict__ ws)
{
    __shared__ float4 sbox[TPER];                 // {x1, x2, y1, y2} (cells role)
    __shared__ unsigned sbm[CELLS_PER_BLK / 32];  // target-cell bitmap (cells role)
    __shared__ float wred[2];
    const int tid = threadIdx.x;                  // 0..127 (2 waves)
    const float aw[3] = {1.25f, 2.0f, 4.125f};
    const float ah[3] = {1.625f, 3.75f, 2.875f};
    const float raw[3] = {0.8f, 0.5f, 0.24242424242424243f};       // 1/aw
    const float rah[3] = {0.6153846153846154f, 0.26666666666666666f, 0.34782608695652173f}; // 1/ah

    float term = 0.0f;
    float flag = 0.0f;

    if (blockIdx.x < NCELLBLK) {
        // ------- cells role: noobj BCE + a_loss, 4 CONSECUTIVE cells/thread -------
        const int b  = blockIdx.x >> 4;           // / CBPB
        const int lo = (blockIdx.x & 15) * CELLS_PER_BLK;
        if (tid < CELLS_PER_BLK / 32) sbm[tid] = 0u;
        int mycell = -1;
        if (tid < TPER) {
            const float* p = tgt + (size_t)(b * TPER + tid) * 5;
            float c0 = p[0], c1 = p[1], c2 = p[2], c3 = p[3], c4 = p[4];
            bool valid = (c0 + c1 + c2 + c3 + c4) > 0.0f;
            float gx = c1 * WW, gy = c2 * HH, gw = c3 * WW, gh = c4 * HH;
            int gi = (int)gx; gi = gi < 0 ? 0 : (gi > WW - 1 ? WW - 1 : gi);
            int gj = (int)gy; gj = gj < 0 ? 0 : (gj > HH - 1 ? HH - 1 : gj);
            // anchor argmax via cross-multiplication; strict > keeps first on tie
            int bn = 0;
            {
                float bi = fminf(gw, aw[0]) * fminf(gh, ah[0]);
                float bu = gw * gh + aw[0] * ah[0] - bi;
                #pragma unroll
                for (int a = 1; a < 3; ++a) {
                    float ia = fminf(gw, aw[a]) * fminf(gh, ah[a]);
                    float ua = gw * gh + aw[a] * ah[a] - ia;
                    if (ia * bu > bi * ua) { bn = a; bi = ia; bu = ua; }
                }
            }
            if (valid) {
                sbox[tid] = make_float4(gx - 0.5f * gw, gx + 0.5f * gw,
                                        gy - 0.5f * gh, gy + 0.5f * gh);
                mycell = bn * HW + gj * WW + gi;
            } else {
                sbox[tid] = make_float4(1e30f, 1e30f, 1e30f, 1e30f);  // inert sentinel
            }
        }
        __syncthreads();
        if (mycell >= lo && mycell < lo + CELLS_PER_BLK)
            atomicOr(&sbm[(mycell - lo) >> 5], 1u << ((mycell - lo) & 31));
        __syncthreads();

        const int q0 = lo + 4 * tid;              // quad base; 4-aligned, CPB%4==0
        const bool actq = q0 < CPB;               // whole quad valid or whole invalid
        float P1[4], P2[4], Q1[4], Q2[4], A2[4], CF[4];
        bool IGN[4] = {false, false, false, false};
        #pragma unroll
        for (int k = 0; k < 4; ++k) { P1[k]=0; P2[k]=0; Q1[k]=0; Q2[k]=0; A2[k]=1e30f; CF[k]=0.5f; }
        if (actq) {
            // HW%4==0, WW%4==0: quad never crosses anchor plane or grid row
            const int a  = q0 / HW;
            const int r  = q0 - a * HW;
            const int yy = r / WW;
            const int xx0 = r - yy * WW;
            const float* plane = in + ((size_t)b * (NA * CH) + a * CH) * HW + r;
            float4 X = *(const float4*)(plane);
            float4 Y = *(const float4*)(plane + HW);
            float4 Wv = *(const float4*)(plane + 2 * HW);
            float4 Hv = *(const float4*)(plane + 3 * HW);
            float4 Cv = *(const float4*)(plane + 4 * HW);
            float xs[4] = {X.x, X.y, X.z, X.w};
            float ys[4] = {Y.x, Y.y, Y.z, Y.w};
            float zs[4] = {Wv.x, Wv.y, Wv.z, Wv.w};
            float hs[4] = {Hv.x, Hv.y, Hv.z, Hv.w};
            float cs[4] = {Cv.x, Cv.y, Cv.z, Cv.w};
            #pragma unroll
            for (int k = 0; k < 4; ++k) {
                float sx = sigm(xs[k]), sy = sigm(ys[k]);
                CF[k] = sigm(cs[k]);
                float px = sx + (float)(xx0 + k), py = sy + (float)yy;
                float pw = fexp(zs[k]) * aw[a], ph = fexp(hs[k]) * ah[a];
                P1[k] = px - 0.5f * pw; P2[k] = px + 0.5f * pw;
                Q1[k] = py - 0.5f * ph; Q2[k] = py + 0.5f * ph;
                A2[k] = pw * ph + 1e-16f;
                term += 0.05f * ((sx - 0.5f) * (sx - 0.5f) + (sy - 0.5f) * (sy - 0.5f)
                                 + zs[k] * zs[k] + hs[k] * hs[k]);   // 0.1/2 pre-weight
            }
        }
        #pragma unroll 2
        for (int t = 0; t < TPER; ++t) {
            float4 bx = sbox[t];                              // one broadcast b128 / target
            float ar = (bx.y - bx.x) * (bx.w - bx.z);         // area1 (0 for sentinel)
            #pragma unroll
            for (int k = 0; k < 4; ++k) {
                float iw = fmaxf(fminf(bx.y, P2[k]) - fmaxf(bx.x, P1[k]), 0.0f);
                float ih = fmaxf(fminf(bx.w, Q2[k]) - fmaxf(bx.z, Q1[k]), 0.0f);
                float inter = iw * ih;
                // iou >= 0.5  <=>  3*inter >= area1 + area2 + eps (denominator > 0)
                IGN[k] = IGN[k] || (3.0f * inter >= ar + A2[k]);
            }
        }
        if (actq) {
            #pragma unroll
            for (int k = 0; k < 4; ++k) {
                int d = 4 * tid + k;
                bool ist = (sbm[d >> 5] >> (d & 31)) & 1u;
                if (!IGN[k] && !ist)
                    term += -flog(fmaxf(1.0f - CF[k], 1e-12f));  // noobj pre-weight 5*0.2=1
            }
        }
    } else {
        // ------- obj role: ONE target per block (128 threads = 2 waves) -------
        const int i = blockIdx.x - NCELLBLK;       // global target index
        const int b = i / TPER;
        const int t = i - b * TPER;
        const int lane = tid & 63;
        const int k = tid;                         // channel index (0..84 used)

        // each wave redundantly preps all 50 targets in registers (no LDS, no barrier)
        int celll = -1, clsl = 0;
        if (lane < TPER) {
            const float* p = tgt + (size_t)(b * TPER + lane) * 5;
            float c0 = p[0], c1 = p[1], c2 = p[2], c3 = p[3], c4 = p[4];
            bool valid = (c0 + c1 + c2 + c3 + c4) > 0.0f;
            float gx = c1 * WW, gy = c2 * HH, gw = c3 * WW, gh = c4 * HH;
            int gi = (int)gx; gi = gi < 0 ? 0 : (gi > WW - 1 ? WW - 1 : gi);
            int gj = (int)gy; gj = gj < 0 ? 0 : (gj > HH - 1 ? HH - 1 : gj);
            int bn = 0;
            {
                float bi = fminf(gw, aw[0]) * fminf(gh, ah[0]);
                float bu = gw * gh + aw[0] * ah[0] - bi;
                #pragma unroll
                for (int a = 1; a < 3; ++a) {
                    float ia = fminf(gw, aw[a]) * fminf(gh, ah[a]);
                    float ua = gw * gh + aw[a] * ah[a] - ia;
                    if (ia * bu > bi * ua) { bn = a; bi = ia; bu = ua; }
                }
            }
            celll = valid ? (bn * HW + gj * WW + gi) : -1;
            int cls = (int)c0; cls = cls < 0 ? 0 : (cls > NC - 1 ? NC - 1 : cls);
            clsl = cls;
        }
        const int cell = __shfl(celll, t);         // my target's cell (wave-uniform)
        bool mt = (lane < TPER) && (cell >= 0) && (celll == cell);
        unsigned long long mask = __ballot(mt);    // valid targets mapping to same cell
        bool owner = (cell >= 0) && ((mask >> (t + 1)) == 0ULL);  // no later writer
        int a = 0, r = 0;
        float v = 0.0f;
        if (cell >= 0 && k < CH) {                 // issue scattered load EARLY
            a = cell / HW;
            r = cell - a * HW;
            v = in[((size_t)b * (NA * CH) + a * CH + k) * HW + r];
        }
        if (owner && k < CH) {
            if (k < 5) {
                const float* p = tgt + (size_t)i * 5;
                if (k == 0) {
                    float gx = p[1] * WW; int gi = r - (r / WW) * WW;
                    float d = sigm(v) - (gx - (float)gi); term = 0.5f * d * d;
                } else if (k == 1) {
                    float gy = p[2] * HH; int gj = r / WW;
                    float d = sigm(v) - (gy - (float)gj); term = 0.5f * d * d;
                } else if (k == 2) {
                    float d = v - flog(p[3] * WW * raw[a] + 1e-16f); term = 0.5f * d * d;
                } else if (k == 3) {
                    float d = v - flog(p[4] * HH * rah[a] + 1e-16f); term = 0.5f * d * d;
                } else {
                    term = -5.0f * flog(fmaxf(sigm(v), 1e-12f));
                }
            } else {
                int c = k - 5;                     // class 0..79
                bool pos = false;                  // multi-hot union over colliding targets
                unsigned long long mm = mask;
                while (mm) {
                    int t2 = __ffsll(mm) - 1; mm &= mm - 1;
                    pos = pos || (__shfl(clsl, t2) == c);   // wave-uniform loop
                }
                float p = sigm(v);
                term = pos ? -flog(fmaxf(p, 1e-12f)) : -flog(fmaxf(1.0f - p, 1e-12f));
            }
        }
        if (tid == 0) flag = (cell >= 0) ? 1.0f : 0.0f;   // n_valid contribution
    }

    // ---- common tail: 2-wave block reduce, one float2 store ----
    float tr = wave_red(term);
    if ((tid & 63) == 0) wred[tid >> 6] = tr;
    __syncthreads();
    if (tid == 0)
        ws[blockIdx.x] = make_float2(wred[0] + wred[1], flag);
}

// Final reduce: 1056 float4 loads; loss = sum(partials) / max(n_valid, 1)
__global__ __launch_bounds__(256) void k_final(const float2* __restrict__ ws,
                                               float* __restrict__ out)
{
    const int tid = threadIdx.x;
    const float4* w4 = (const float4*)ws;          // NBLK/2 = 1056 float4
    float s = 0.0f, nv = 0.0f;
    for (int i = tid; i < NBLK / 2; i += 256) {
        float4 v = w4[i];
        s += v.x + v.z;
        nv += v.y + v.w;
    }
    __shared__ float wr0[4], wr1[4];
    s = wave_red(s);
    nv = wave_red(nv);
    if ((tid & 63) == 0) { wr0[tid >> 6] = s; wr1[tid >> 6] = nv; }
    __syncthreads();
    if (tid == 0) {
        float S = wr0[0] + wr0[1] + wr0[2] + wr0[3];
        float N = wr1[0] + wr1[1] + wr1[2] + wr1[3];
        out[0] = S / fmaxf(N, 1.0f);
    }
}

extern "C" void kernel_launch(void* const* d_in, const int* in_sizes, int n_in,
                              void* d_out, int out_size, void* d_ws, size_t ws_size,
                              hipStream_t stream)
{
    const float* in = (const float*)d_in[0];
    const float* tgt = (const float*)d_in[1];
    float2* ws = (float2*)d_ws;

    k_main<<<NBLK, 128, 0, stream>>>(in, tgt, ws);
    k_final<<<1, 256, 0, stream>>>(ws, (float*)d_out);
}

// Round 13
// 17.259 us; speedup vs baseline: 1.2442x; 1.2442x over previous
//
#include <hip/hip_runtime.h>
#include <math.h>

// Problem constants (match reference setup_inputs)
#define BS 32
#define NA 3
#define NC 80
#define HH 52
#define WW 52
#define TPER 50                 // targets per batch image
#define NTT (BS * TPER)         // 1600 total targets
#define HW (HH * WW)            // 2704
#define CPB (NA * HW)           // 8112 cells per batch image (divisible by 4)
#define CH (5 + NC)             // 85 channels per anchor
#define CELLS_PER_BLK 1024      // 256 threads x 4 CONSECUTIVE cells each
#define CBPB 8                  // cell-blocks per batch: 8*1024 >= 8112
#define NCELLBLK (BS * CBPB)    // 256 cells-role blocks
#define OBJ_QPB 13              // 4-target quads per batch (13*4 >= 50)
#define NOBJBLK (BS * OBJ_QPB)  // 416 obj blocks
#define NBLK (NCELLBLK + NOBJBLK) // 672 blocks (even)

// fast transcendentals: v_exp_f32 (2^x), v_log_f32 (log2 x), v_rcp_f32
__device__ __forceinline__ float fexp(float x) { return __builtin_amdgcn_exp2f(x * 1.4426950408889634f); }
__device__ __forceinline__ float flog(float x) { return __builtin_amdgcn_logf(x) * 0.6931471805599453f; }
__device__ __forceinline__ float sigm(float v) { return __builtin_amdgcn_rcpf(1.0f + fexp(-v)); }

__device__ __forceinline__ float wave_red(float t) {
    #pragma unroll
    for (int off = 32; off > 0; off >>= 1) t += __shfl_down(t, off);  // width 64
    return t;
}

// ws layout: float2 ws[NBLK] = {pre-weighted loss partial, n_valid contribution}

__global__ __launch_bounds__(256) void k_main(const float* __restrict__ in,
                                              const float* __restrict__ tgt,
                                              float2* __restrict__ ws)
{
    __shared__ float4 sbox[TPER];                 // {x1, x2, y1, y2} (cells role)
    __shared__ unsigned sbm[CELLS_PER_BLK / 32];  // target-cell bitmap (cells role)
    __shared__ float wred[4];
    const int tid = threadIdx.x;
    const float aw[3] = {1.25f, 2.0f, 4.125f};
    const float ah[3] = {1.625f, 3.75f, 2.875f};
    const float raw[3] = {0.8f, 0.5f, 0.24242424242424243f};       // 1/aw
    const float rah[3] = {0.6153846153846154f, 0.26666666666666666f, 0.34782608695652173f}; // 1/ah

    float term = 0.0f;
    float flag = 0.0f;

    if (blockIdx.x < NCELLBLK) {
        // ------- cells role: noobj BCE + a_loss, 4 CONSECUTIVE cells/thread -------
        // (exactly the round-10 best-measured variant)
        const int b  = blockIdx.x >> 3;           // / CBPB
        const int lo = (blockIdx.x & 7) * CELLS_PER_BLK;
        if (tid < CELLS_PER_BLK / 32) sbm[tid] = 0u;
        int mycell = -1;
        if (tid < TPER) {
            const float* p = tgt + (size_t)(b * TPER + tid) * 5;
            float c0 = p[0], c1 = p[1], c2 = p[2], c3 = p[3], c4 = p[4];
            bool valid = (c0 + c1 + c2 + c3 + c4) > 0.0f;
            float gx = c1 * WW, gy = c2 * HH, gw = c3 * WW, gh = c4 * HH;
            int gi = (int)gx; gi = gi < 0 ? 0 : (gi > WW - 1 ? WW - 1 : gi);
            int gj = (int)gy; gj = gj < 0 ? 0 : (gj > HH - 1 ? HH - 1 : gj);
            // anchor argmax via cross-multiplication; strict > keeps first on tie
            int bn = 0;
            {
                float bi = fminf(gw, aw[0]) * fminf(gh, ah[0]);
                float bu = gw * gh + aw[0] * ah[0] - bi;
                #pragma unroll
                for (int a = 1; a < 3; ++a) {
                    float ia = fminf(gw, aw[a]) * fminf(gh, ah[a]);
                    float ua = gw * gh + aw[a] * ah[a] - ia;
                    if (ia * bu > bi * ua) { bn = a; bi = ia; bu = ua; }
                }
            }
            if (valid) {
                sbox[tid] = make_float4(gx - 0.5f * gw, gx + 0.5f * gw,
                                        gy - 0.5f * gh, gy + 0.5f * gh);
                mycell = bn * HW + gj * WW + gi;
            } else {
                sbox[tid] = make_float4(1e30f, 1e30f, 1e30f, 1e30f);  // inert sentinel
            }
        }
        __syncthreads();
        if (mycell >= lo && mycell < lo + CELLS_PER_BLK)
            atomicOr(&sbm[(mycell - lo) >> 5], 1u << ((mycell - lo) & 31));
        __syncthreads();

        const int q0 = lo + 4 * tid;              // quad base; 4-aligned, CPB%4==0
        const bool actq = q0 < CPB;               // whole quad valid or whole invalid
        float P1[4], P2[4], Q1[4], Q2[4], A2[4], CF[4];
        bool IGN[4] = {false, false, false, false};
        #pragma unroll
        for (int k = 0; k < 4; ++k) { P1[k]=0; P2[k]=0; Q1[k]=0; Q2[k]=0; A2[k]=1e30f; CF[k]=0.5f; }
        if (actq) {
            // HW%4==0, WW%4==0: quad never crosses anchor plane or grid row
            const int a  = q0 / HW;
            const int r  = q0 - a * HW;
            const int yy = r / WW;
            const int xx0 = r - yy * WW;
            const float* plane = in + ((size_t)b * (NA * CH) + a * CH) * HW + r;
            float4 X = *(const float4*)(plane);
            float4 Y = *(const float4*)(plane + HW);
            float4 Wv = *(const float4*)(plane + 2 * HW);
            float4 Hv = *(const float4*)(plane + 3 * HW);
            float4 Cv = *(const float4*)(plane + 4 * HW);
            float xs[4] = {X.x, X.y, X.z, X.w};
            float ys[4] = {Y.x, Y.y, Y.z, Y.w};
            float zs[4] = {Wv.x, Wv.y, Wv.z, Wv.w};
            float hs[4] = {Hv.x, Hv.y, Hv.z, Hv.w};
            float cs[4] = {Cv.x, Cv.y, Cv.z, Cv.w};
            #pragma unroll
            for (int k = 0; k < 4; ++k) {
                float sx = sigm(xs[k]), sy = sigm(ys[k]);
                CF[k] = sigm(cs[k]);
                float px = sx + (float)(xx0 + k), py = sy + (float)yy;
                float pw = fexp(zs[k]) * aw[a], ph = fexp(hs[k]) * ah[a];
                P1[k] = px - 0.5f * pw; P2[k] = px + 0.5f * pw;
                Q1[k] = py - 0.5f * ph; Q2[k] = py + 0.5f * ph;
                A2[k] = pw * ph + 1e-16f;
                term += 0.05f * ((sx - 0.5f) * (sx - 0.5f) + (sy - 0.5f) * (sy - 0.5f)
                                 + zs[k] * zs[k] + hs[k] * hs[k]);   // 0.1/2 pre-weight
            }
        }
        #pragma unroll 2
        for (int t = 0; t < TPER; ++t) {
            float4 bx = sbox[t];                              // one broadcast b128 / target
            float ar = (bx.y - bx.x) * (bx.w - bx.z);         // area1 (0 for sentinel)
            #pragma unroll
            for (int k = 0; k < 4; ++k) {
                float iw = fmaxf(fminf(bx.y, P2[k]) - fmaxf(bx.x, P1[k]), 0.0f);
                float ih = fmaxf(fminf(bx.w, Q2[k]) - fmaxf(bx.z, Q1[k]), 0.0f);
                float inter = iw * ih;
                // iou >= 0.5  <=>  3*inter >= area1 + area2 + eps (denominator > 0)
                IGN[k] = IGN[k] || (3.0f * inter >= ar + A2[k]);
            }
        }
        if (actq) {
            #pragma unroll
            for (int k = 0; k < 4; ++k) {
                int d = 4 * tid + k;
                bool ist = (sbm[d >> 5] >> (d & 31)) & 1u;
                if (!IGN[k] && !ist)
                    term += -flog(fmaxf(1.0f - CF[k], 1e-12f));  // noobj pre-weight 5*0.2=1
            }
        }
    } else {
        // ------- obj role: FOUR targets per block, one wave per target -------
        const int o = blockIdx.x - NCELLBLK;       // 0..NOBJBLK-1
        const int b = o / OBJ_QPB;
        const int quad = o - b * OBJ_QPB;
        const int tA = 4 * quad;                   // 0,4,...,48
        const int lane = tid & 63;
        const int wid = tid >> 6;                  // 0..3
        const int myT = tA + wid;                  // may be >= TPER (tail quad) -> inert

        // every wave redundantly preps all 50 targets in registers (no LDS, no barrier)
        int celll = -1, clsl = 0;
        if (lane < TPER) {
            const float* p = tgt + (size_t)(b * TPER + lane) * 5;
            float c0 = p[0], c1 = p[1], c2 = p[2], c3 = p[3], c4 = p[4];
            bool valid = (c0 + c1 + c2 + c3 + c4) > 0.0f;
            float gx = c1 * WW, gy = c2 * HH, gw = c3 * WW, gh = c4 * HH;
            int gi = (int)gx; gi = gi < 0 ? 0 : (gi > WW - 1 ? WW - 1 : gi);
            int gj = (int)gy; gj = gj < 0 ? 0 : (gj > HH - 1 ? HH - 1 : gj);
            int bn = 0;
            {
                float bi = fminf(gw, aw[0]) * fminf(gh, ah[0]);
                float bu = gw * gh + aw[0] * ah[0] - bi;
                #pragma unroll
                for (int a = 1; a < 3; ++a) {
                    float ia = fminf(gw, aw[a]) * fminf(gh, ah[a]);
                    float ua = gw * gh + aw[a] * ah[a] - ia;
                    if (ia * bu > bi * ua) { bn = a; bi = ia; bu = ua; }
                }
            }
            celll = valid ? (bn * HW + gj * WW + gi) : -1;
            int cls = (int)c0; cls = cls < 0 ? 0 : (cls > NC - 1 ? NC - 1 : cls);
            clsl = cls;
        }
        // myT <= 51 < 64; lanes >= TPER hold celll = -1, so tail quads are inert
        const int cell = __shfl(celll, myT);       // my wave's target cell (uniform)
        bool mt = (lane < TPER) && (cell >= 0) && (celll == cell);
        unsigned long long mask = __ballot(mt);    // valid targets mapping to same cell
        bool owner = (cell >= 0) && ((mask >> (myT + 1)) == 0ULL);  // no later writer
        int a = 0, r = 0;
        float v1 = 0.0f, v2 = 0.0f;
        if (cell >= 0) {                           // issue scattered loads EARLY
            a = cell / HW;
            r = cell - a * HW;
            const float* bp = in + ((size_t)b * (NA * CH) + a * CH) * HW + r;
            v1 = bp[(size_t)lane * HW];            // channel = lane (0..63)
            if (lane < CH - 64) v2 = bp[(size_t)(lane + 64) * HW];  // channel 64..84
        }
        if (owner) {                               // owner is wave-uniform
            // channel k1 = lane
            if (lane < 5) {
                const float* p = tgt + (size_t)(b * TPER + myT) * 5;
                if (lane == 0) {
                    float gx = p[1] * WW; int gi = r - (r / WW) * WW;
                    float d = sigm(v1) - (gx - (float)gi); term = 0.5f * d * d;
                } else if (lane == 1) {
                    float gy = p[2] * HH; int gj = r / WW;
                    float d = sigm(v1) - (gy - (float)gj); term = 0.5f * d * d;
                } else if (lane == 2) {
                    float d = v1 - flog(p[3] * WW * raw[a] + 1e-16f); term = 0.5f * d * d;
                } else if (lane == 3) {
                    float d = v1 - flog(p[4] * HH * rah[a] + 1e-16f); term = 0.5f * d * d;
                } else {
                    term = -5.0f * flog(fmaxf(sigm(v1), 1e-12f));
                }
            }
            // class-positive test for both channels in ONE set-bit loop
            int c1 = lane - 5;                     // class of k1 (valid if lane >= 5)
            int c2 = lane + 59;                    // class of k2 = lane+64 (if < 80)
            bool pos1 = false, pos2 = false;
            unsigned long long mm = mask;
            while (mm) {
                int t2 = __ffsll(mm) - 1; mm &= mm - 1;
                int cc = __shfl(clsl, t2);         // wave-uniform loop, shfl safe
                pos1 = pos1 || (cc == c1);
                pos2 = pos2 || (cc == c2);
            }
            if (lane >= 5) {
                float p = sigm(v1);
                term = pos1 ? -flog(fmaxf(p, 1e-12f)) : -flog(fmaxf(1.0f - p, 1e-12f));
            }
            if (lane < CH - 64) {                  // second channel (classes 59..79)
                float p = sigm(v2);
                term += pos2 ? -flog(fmaxf(p, 1e-12f)) : -flog(fmaxf(1.0f - p, 1e-12f));
            }
        }
        if (wid == 0) {                            // n_valid for the quad (read at tid 0)
            float f = 0.0f;
            #pragma unroll
            for (int j = 0; j < 4; ++j) {
                int tj = tA + j;
                int cj = (tj < TPER) ? __shfl(celll, tj) : -1;
                f += (cj >= 0) ? 1.0f : 0.0f;
            }
            flag = f;
        }
    }

    // ---- common tail: block reduce, one float2 store ----
    float tr = wave_red(term);
    if ((tid & 63) == 0) wred[tid >> 6] = tr;
    __syncthreads();
    if (tid == 0)
        ws[blockIdx.x] = make_float2(wred[0] + wred[1] + wred[2] + wred[3], flag);
}

// Final reduce: 336 float4 loads; loss = sum(partials) / max(n_valid, 1)
__global__ __launch_bounds__(256) void k_final(const float2* __restrict__ ws,
                                               float* __restrict__ out)
{
    const int tid = threadIdx.x;
    const float4* w4 = (const float4*)ws;          // NBLK/2 = 336 float4
    float s = 0.0f, nv = 0.0f;
    for (int i = tid; i < NBLK / 2; i += 256) {
        float4 v = w4[i];
        s += v.x + v.z;
        nv += v.y + v.w;
    }
    __shared__ float wr0[4], wr1[4];
    s = wave_red(s);
    nv = wave_red(nv);
    if ((tid & 63) == 0) { wr0[tid >> 6] = s; wr1[tid >> 6] = nv; }
    __syncthreads();
    if (tid == 0) {
        float S = wr0[0] + wr0[1] + wr0[2] + wr0[3];
        float N = wr1[0] + wr1[1] + wr1[2] + wr1[3];
        out[0] = S / fmaxf(N, 1.0f);
    }
}

extern "C" void kernel_launch(void* const* d_in, const int* in_sizes, int n_in,
                              void* d_out, int out_size, void* d_ws, size_t ws_size,
                              hipStream_t stream)
{
    const float* in = (const float*)d_in[0];
    const float* tgt = (const float*)d_in[1];
    float2* ws = (float2*)d_ws;

    k_main<<<NBLK, 256, 0, stream>>>(in, tgt, ws);
    k_final<<<1, 256, 0, stream>>>(ws, (float*)d_out);
}